// Round 1
// baseline (533.463 us; speedup 1.0000x reference)
//
#include <hip/hip_runtime.h>
#include <math.h>

typedef __bf16 bf16_t;
typedef bf16_t bf16x8 __attribute__((ext_vector_type(8)));
typedef float  floatx4 __attribute__((ext_vector_type(4)));

#define MFMA16(a, b, c) __builtin_amdgcn_mfma_f32_16x16x32_bf16((a), (b), (c), 0, 0, 0)

// Problem constants
constexpr int NTOT = 256 * 512;   // 131072 samples
constexpr int CDIM = 256;         // central state dim (K for all GEMMs)
// ws layout (bf16 elements), all matrices stored column-major T[out][k], k-stride 256
constexpr int OFF_T1A  = 0;        // w1a  [256->256]
constexpr int OFF_T1B  = 65536;    // w1b  [256->512]
constexpr int OFF_T2A  = 196608;   // w2a  [256->256]
constexpr int OFF_T2B  = 262144;   // w2b  [256->64]
constexpr int OFF_TB1  = 278528;   // wb1  [256->64]
constexpr int OFF_TB2A = 294912;   // wb2a [256->256]
constexpr int WS_ELEMS = 360448;

// ---------------------------------------------------------------------------
// Prep: transpose + fp32->bf16 all six weight matrices into workspace.
// dst layout: T[o][i] = W[i][o], i (=k) contiguous with stride 256.
// ---------------------------------------------------------------------------
__global__ void prep_weights(const float* __restrict__ w1a, const float* __restrict__ w1b,
                             const float* __restrict__ w2a, const float* __restrict__ w2b,
                             const float* __restrict__ wb1, const float* __restrict__ wb2a,
                             bf16_t* __restrict__ ws) {
  int idx = blockIdx.x * 256 + threadIdx.x;
  if (idx >= WS_ELEMS) return;
  const float* src; int dout; int rel;
  if      (idx < OFF_T1B)  { src = w1a;  dout = 256; rel = idx; }
  else if (idx < OFF_T2A)  { src = w1b;  dout = 512; rel = idx - OFF_T1B; }
  else if (idx < OFF_T2B)  { src = w2a;  dout = 256; rel = idx - OFF_T2A; }
  else if (idx < OFF_TB1)  { src = w2b;  dout = 64;  rel = idx - OFF_T2B; }
  else if (idx < OFF_TB2A) { src = wb1;  dout = 64;  rel = idx - OFF_TB1; }
  else                     { src = wb2a; dout = 256; rel = idx - OFF_TB2A; }
  int o = rel >> 8;          // output column
  int i = rel & 255;         // k index
  ws[idx] = (bf16_t)src[(size_t)i * dout + o];
}

// ---------------------------------------------------------------------------
// Fused mixing network.
// Block = 256 threads = 4 waves. Wave owns 32 rows (2 x 16-row MFMA tiles).
// Block covers 128 rows. Grid = NTOT/128 = 1024 blocks. No __syncthreads:
// each wave reads/writes only its own 32 LDS rows.
//
// MFMA 16x16x32 bf16 layouts (guide §3, HW-verified):
//   A: m = lane&15, k = (lane>>4)*8 + j          (8 bf16 per lane)
//   B: n = lane&15, k = (lane>>4)*8 + j
//   C/D: col = lane&15, row = (lane>>4)*4 + reg
// ---------------------------------------------------------------------------
__global__ __launch_bounds__(256, 2)
void mixing_fused(const float* __restrict__ q,     // [N,8]
                  const float* __restrict__ st,    // [N,256]
                  const bf16_t* __restrict__ W,    // ws (bf16 transposed weights)
                  const float* __restrict__ b1a, const float* __restrict__ b1b,
                  const float* __restrict__ b2a, const float* __restrict__ b2b,
                  const float* __restrict__ bb1,
                  const float* __restrict__ bb2a,
                  const float* __restrict__ wb2b, const float* __restrict__ bb2b,
                  float* __restrict__ out) {
  __shared__ __align__(16) bf16_t h_s[128][264];   // 264 = 256 + 8 pad (bank decorrelation)

  const int tid  = threadIdx.x;
  const int wid  = tid >> 6;
  const int lane = tid & 63;
  const int l15  = lane & 15;
  const int quad = lane >> 4;
  const int m0   = blockIdx.x * 128 + wid * 32;    // first global row of this wave
  const int lrow = wid * 32 + l15;                 // LDS A-frag row base (add rt*16)

  // ---- load st A-fragments straight from global (coalesced), cvt to bf16 ----
  bf16x8 sA[2][8];
#pragma unroll
  for (int rt = 0; rt < 2; ++rt) {
    const float* rp = st + (size_t)(m0 + rt * 16 + l15) * CDIM;
#pragma unroll
    for (int ks = 0; ks < 8; ++ks) {
      int k0 = ks * 32 + quad * 8;
      float4 f0 = *(const float4*)(rp + k0);
      float4 f1 = *(const float4*)(rp + k0 + 4);
      bf16x8 v;
      v[0] = (bf16_t)f0.x; v[1] = (bf16_t)f0.y; v[2] = (bf16_t)f0.z; v[3] = (bf16_t)f0.w;
      v[4] = (bf16_t)f1.x; v[5] = (bf16_t)f1.y; v[6] = (bf16_t)f1.z; v[7] = (bf16_t)f1.w;
      sA[rt][ks] = v;
    }
  }

  // GEMM over one 16-col tile, both row tiles: acc[rt] = A(rt) * T[:, ct*16..+16]
  auto gemm16 = [&](const bf16_t* __restrict__ T, const bf16x8 (&A)[2][8], int ct,
                    floatx4 (&acc)[2]) {
    floatx4 z = {0.f, 0.f, 0.f, 0.f};
    acc[0] = z; acc[1] = z;
#pragma unroll
    for (int ks = 0; ks < 8; ++ks) {
      bf16x8 b = *(const bf16x8*)(T + ((size_t)(ct * 16 + l15) << 8) + ks * 32 + quad * 8);
      acc[0] = MFMA16(A[0][ks], b, acc[0]);
      acc[1] = MFMA16(A[1][ks], b, acc[1]);
    }
  };

  // ================= Phase A: H1 = elu(st @ w1a + b1a) -> LDS ================
#pragma unroll 1
  for (int ct = 0; ct < 16; ++ct) {
    floatx4 acc[2];
    gemm16(W + OFF_T1A, sA, ct, acc);
    float bias = b1a[ct * 16 + l15];
#pragma unroll
    for (int rt = 0; rt < 2; ++rt)
#pragma unroll
      for (int i = 0; i < 4; ++i) {
        float v = acc[rt][i] + bias;
        v = v > 0.f ? v : (__expf(v) - 1.f);
        h_s[wid * 32 + rt * 16 + quad * 4 + i][ct * 16 + l15] = (bf16_t)v;
      }
  }
  // H1 A-fragments
  bf16x8 hA[2][8];
#pragma unroll
  for (int rt = 0; rt < 2; ++rt)
#pragma unroll
    for (int ks = 0; ks < 8; ++ks)
      hA[rt][ks] = *(const bf16x8*)&h_s[lrow + rt * 16][ks * 32 + quad * 8];

  // ================= Phase B1: hidden = st @ wb1 + bb1 =======================
  floatx4 hid[2][4];
#pragma unroll
  for (int et = 0; et < 4; ++et) {
    floatx4 acc[2];
    gemm16(W + OFF_TB1, sA, et, acc);
    float bias = bb1[et * 16 + l15];
    hid[0][et] = acc[0] + bias;
    hid[1][et] = acc[1] + bias;
  }

  // ====== Phase B2: W1 = |H1 @ w1b + b1b|; hidden += q[:,a] * W1[:,a,:] ======
#pragma unroll 1
  for (int a = 0; a < 8; ++a) {
#pragma unroll
    for (int et = 0; et < 4; ++et) {
      int ct = a * 4 + et;
      floatx4 acc[2];
      gemm16(W + OFF_T1B, hA, ct, acc);
      float bias = b1b[ct * 16 + l15];
#pragma unroll
      for (int rt = 0; rt < 2; ++rt)
#pragma unroll
        for (int i = 0; i < 4; ++i) {
          float w1v = fabsf(acc[rt][i] + bias);
          float qv  = q[(size_t)(m0 + rt * 16 + quad * 4 + i) * 8 + a];
          hid[rt][et][i] += qv * w1v;
        }
    }
  }
  // relu
#pragma unroll
  for (int rt = 0; rt < 2; ++rt)
#pragma unroll
    for (int et = 0; et < 4; ++et)
#pragma unroll
      for (int i = 0; i < 4; ++i) hid[rt][et][i] = fmaxf(hid[rt][et][i], 0.f);

  // ================= Phase C: H2 = elu(st @ w2a + b2a) -> LDS ================
#pragma unroll 1
  for (int ct = 0; ct < 16; ++ct) {
    floatx4 acc[2];
    gemm16(W + OFF_T2A, sA, ct, acc);
    float bias = b2a[ct * 16 + l15];
#pragma unroll
    for (int rt = 0; rt < 2; ++rt)
#pragma unroll
      for (int i = 0; i < 4; ++i) {
        float v = acc[rt][i] + bias;
        v = v > 0.f ? v : (__expf(v) - 1.f);
        h_s[wid * 32 + rt * 16 + quad * 4 + i][ct * 16 + l15] = (bf16_t)v;
      }
  }
#pragma unroll
  for (int rt = 0; rt < 2; ++rt)
#pragma unroll
    for (int ks = 0; ks < 8; ++ks)
      hA[rt][ks] = *(const bf16x8*)&h_s[lrow + rt * 16][ks * 32 + quad * 8];

  // ====== Phase D: W2 = |H2 @ w2b + b2b|; pj = sum_e hidden*W2 (partial) =====
  float pj[2][4] = {{0.f, 0.f, 0.f, 0.f}, {0.f, 0.f, 0.f, 0.f}};
#pragma unroll
  for (int et = 0; et < 4; ++et) {
    floatx4 acc[2];
    gemm16(W + OFF_T2B, hA, et, acc);
    float bias = b2b[et * 16 + l15];
#pragma unroll
    for (int rt = 0; rt < 2; ++rt)
#pragma unroll
      for (int i = 0; i < 4; ++i) {
        float w2v = fabsf(acc[rt][i] + bias);
        pj[rt][i] += hid[rt][et][i] * w2v;
      }
  }

  // == Phase E: HB = elu(st @ wb2a + bb2a); pb = HB @ wb2b (fused in epilogue) =
  float pb[2][4] = {{0.f, 0.f, 0.f, 0.f}, {0.f, 0.f, 0.f, 0.f}};
#pragma unroll 1
  for (int ct = 0; ct < 16; ++ct) {
    floatx4 acc[2];
    gemm16(W + OFF_TB2A, sA, ct, acc);
    float bias = bb2a[ct * 16 + l15];
    float wv   = wb2b[ct * 16 + l15];
#pragma unroll
    for (int rt = 0; rt < 2; ++rt)
#pragma unroll
      for (int i = 0; i < 4; ++i) {
        float v = acc[rt][i] + bias;
        v = v > 0.f ? v : (__expf(v) - 1.f);
        pb[rt][i] += v * wv;
      }
  }

  // ======= Reduce over 16 column lanes (same row), store joint output ========
  float bb2 = bb2b[0];
#pragma unroll
  for (int rt = 0; rt < 2; ++rt)
#pragma unroll
    for (int i = 0; i < 4; ++i) {
      float v = pj[rt][i] + pb[rt][i];
      v += __shfl_xor(v, 1);
      v += __shfl_xor(v, 2);
      v += __shfl_xor(v, 4);
      v += __shfl_xor(v, 8);
      if (l15 == 0) out[m0 + rt * 16 + quad * 4 + i] = v + bb2;
    }
}

// ---------------------------------------------------------------------------
extern "C" void kernel_launch(void* const* d_in, const int* in_sizes, int n_in,
                              void* d_out, int out_size, void* d_ws, size_t ws_size,
                              hipStream_t stream) {
  const float* q    = (const float*)d_in[0];
  const float* st   = (const float*)d_in[1];
  const float* w1a  = (const float*)d_in[2];
  const float* b1a  = (const float*)d_in[3];
  const float* w1b  = (const float*)d_in[4];
  const float* b1b  = (const float*)d_in[5];
  const float* w2a  = (const float*)d_in[6];
  const float* b2a  = (const float*)d_in[7];
  const float* w2b  = (const float*)d_in[8];
  const float* b2b  = (const float*)d_in[9];
  const float* wb1  = (const float*)d_in[10];
  const float* bb1  = (const float*)d_in[11];
  const float* wb2a = (const float*)d_in[12];
  const float* bb2a = (const float*)d_in[13];
  const float* wb2b = (const float*)d_in[14];
  const float* bb2b = (const float*)d_in[15];
  bf16_t* W = (bf16_t*)d_ws;

  hipLaunchKernelGGL(prep_weights, dim3((WS_ELEMS + 255) / 256), dim3(256), 0, stream,
                     w1a, w1b, w2a, w2b, wb1, wb2a, W);
  hipLaunchKernelGGL(mixing_fused, dim3(NTOT / 128), dim3(256), 0, stream,
                     q, st, W, b1a, b1b, b2a, b2b, bb1, bb2a, wb2b, bb2b, (float*)d_out);
}

// Round 2
// 420.012 us; speedup vs baseline: 1.2701x; 1.2701x over previous
//
#include <hip/hip_runtime.h>
#include <math.h>

typedef __bf16 bf16_t;
typedef bf16_t bf16x8 __attribute__((ext_vector_type(8)));
typedef float  floatx4 __attribute__((ext_vector_type(4)));

#define MFMA16(a, b, c) __builtin_amdgcn_mfma_f32_16x16x32_bf16((a), (b), (c), 0, 0, 0)

// Problem constants
constexpr int NTOT = 256 * 512;   // 131072 samples
constexpr int CDIM = 256;         // central state dim (K for all GEMMs)
// ws layout (bf16 elements). Each matrix stored in MFMA B-fragment order:
//   W'[ct][ks][lane][j]  (lane = quad*16 + n), value = W[k = ks*32+quad*8+j][o = ct*16+n]
// so one wave B-load = 1024 contiguous bytes at (ct*8+ks)*512 elements + lane*8.
constexpr int OFF_T1A  = 0;        // w1a  [256->256]
constexpr int OFF_T1B  = 65536;    // w1b  [256->512]
constexpr int OFF_T2A  = 196608;   // w2a  [256->256]
constexpr int OFF_T2B  = 262144;   // w2b  [256->64]
constexpr int OFF_TB1  = 278528;   // wb1  [256->64]
constexpr int OFF_TB2A = 294912;   // wb2a [256->256]
constexpr int WS_ELEMS = 360448;

// ---------------------------------------------------------------------------
// Prep: fp32->bf16 + swizzle into MFMA fragment order.
// ---------------------------------------------------------------------------
__global__ void prep_weights(const float* __restrict__ w1a, const float* __restrict__ w1b,
                             const float* __restrict__ w2a, const float* __restrict__ w2b,
                             const float* __restrict__ wb1, const float* __restrict__ wb2a,
                             bf16_t* __restrict__ ws) {
  int idx = blockIdx.x * 256 + threadIdx.x;
  if (idx >= WS_ELEMS) return;
  const float* src; int dout; int rel;
  if      (idx < OFF_T1B)  { src = w1a;  dout = 256; rel = idx; }
  else if (idx < OFF_T2A)  { src = w1b;  dout = 512; rel = idx - OFF_T1B; }
  else if (idx < OFF_T2B)  { src = w2a;  dout = 256; rel = idx - OFF_T2A; }
  else if (idx < OFF_TB1)  { src = w2b;  dout = 64;  rel = idx - OFF_T2B; }
  else if (idx < OFF_TB2A) { src = wb1;  dout = 64;  rel = idx - OFF_TB1; }
  else                     { src = wb2a; dout = 256; rel = idx - OFF_TB2A; }
  int j    = rel & 7;
  int lane = (rel >> 3) & 63;
  int ks   = (rel >> 9) & 7;
  int ct   = rel >> 12;
  int n  = lane & 15;
  int qd = lane >> 4;
  int o  = ct * 16 + n;
  int k  = ks * 32 + qd * 8 + j;
  ws[idx] = (bf16_t)src[(size_t)k * dout + o];
}

// ---------------------------------------------------------------------------
// Fused mixing network.
// Block = 256 threads = 4 waves. Wave owns 32 rows (2 x 16-row MFMA tiles).
// Block covers 128 rows. Grid = 1024 blocks. No __syncthreads (wave-local LDS).
//
// MFMA 16x16x32 bf16 layouts (guide §3, HW-verified):
//   A: m = lane&15, k = (lane>>4)*8 + j          (8 bf16 per lane)
//   B: n = lane&15, k = (lane>>4)*8 + j
//   C/D: col = lane&15, row = (lane>>4)*4 + reg
// ---------------------------------------------------------------------------
__global__ __launch_bounds__(256, 2)
void mixing_fused(const float* __restrict__ q,     // [N,8]
                  const float* __restrict__ st,    // [N,256]
                  const bf16_t* __restrict__ W,    // ws (bf16 fragment-order weights)
                  const float* __restrict__ b1a, const float* __restrict__ b1b,
                  const float* __restrict__ b2a, const float* __restrict__ b2b,
                  const float* __restrict__ bb1,
                  const float* __restrict__ bb2a,
                  const float* __restrict__ wb2b, const float* __restrict__ bb2b,
                  float* __restrict__ out) {
  __shared__ __align__(16) bf16_t h_s[128][264];   // 264 = 256 + 8 pad
  __shared__ __align__(16) float  q_s[4][256];     // per-wave q staging [32 rows][8]

  const int tid  = threadIdx.x;
  const int wid  = tid >> 6;
  const int lane = tid & 63;
  const int l15  = lane & 15;
  const int quad = lane >> 4;
  const int m0   = blockIdx.x * 128 + wid * 32;    // first global row of this wave
  const int lrow = wid * 32 + l15;                 // LDS A-frag row base (add rt*16)

  // ---- stage q for this wave's 32 rows (coalesced), wave-local, no barrier ----
  *(float4*)&q_s[wid][lane * 4] = *(const float4*)(q + (size_t)m0 * 8 + lane * 4);

  // ---- load st A-fragments straight from global (coalesced), cvt to bf16 ----
  bf16x8 sA[2][8];
#pragma unroll
  for (int rt = 0; rt < 2; ++rt) {
    const float* rp = st + (size_t)(m0 + rt * 16 + l15) * CDIM;
#pragma unroll
    for (int ks = 0; ks < 8; ++ks) {
      int k0 = ks * 32 + quad * 8;
      float4 f0 = *(const float4*)(rp + k0);
      float4 f1 = *(const float4*)(rp + k0 + 4);
      bf16x8 v;
      v[0] = (bf16_t)f0.x; v[1] = (bf16_t)f0.y; v[2] = (bf16_t)f0.z; v[3] = (bf16_t)f0.w;
      v[4] = (bf16_t)f1.x; v[5] = (bf16_t)f1.y; v[6] = (bf16_t)f1.z; v[7] = (bf16_t)f1.w;
      sA[rt][ks] = v;
    }
  }

  // GEMM over one 16-col tile, both row tiles. B-loads are fully coalesced
  // (1 KB contiguous per instruction thanks to fragment-order weight layout).
  auto gemm16 = [&](const bf16_t* __restrict__ T, const bf16x8 (&A)[2][8], int ct,
                    floatx4 (&acc)[2]) {
    floatx4 z = {0.f, 0.f, 0.f, 0.f};
    acc[0] = z; acc[1] = z;
#pragma unroll
    for (int ks = 0; ks < 8; ++ks) {
      bf16x8 b = *(const bf16x8*)(T + (((size_t)(ct * 8 + ks)) << 9) + (lane << 3));
      acc[0] = MFMA16(A[0][ks], b, acc[0]);
      acc[1] = MFMA16(A[1][ks], b, acc[1]);
    }
  };

  // ================= Phase A: H1 = elu(st @ w1a + b1a) -> LDS ================
#pragma unroll 2
  for (int ct = 0; ct < 16; ++ct) {
    floatx4 acc[2];
    gemm16(W + OFF_T1A, sA, ct, acc);
    float bias = b1a[ct * 16 + l15];
#pragma unroll
    for (int rt = 0; rt < 2; ++rt)
#pragma unroll
      for (int i = 0; i < 4; ++i) {
        float v = acc[rt][i] + bias;
        v = v > 0.f ? v : (__expf(v) - 1.f);
        h_s[wid * 32 + rt * 16 + quad * 4 + i][ct * 16 + l15] = (bf16_t)v;
      }
  }
  // H1 A-fragments
  bf16x8 hA[2][8];
#pragma unroll
  for (int rt = 0; rt < 2; ++rt)
#pragma unroll
    for (int ks = 0; ks < 8; ++ks)
      hA[rt][ks] = *(const bf16x8*)&h_s[lrow + rt * 16][ks * 32 + quad * 8];

  // ================= Phase B1: hidden = st @ wb1 + bb1 =======================
  floatx4 hid[2][4];
#pragma unroll
  for (int et = 0; et < 4; ++et) {
    floatx4 acc[2];
    gemm16(W + OFF_TB1, sA, et, acc);
    float bias = bb1[et * 16 + l15];
    hid[0][et] = acc[0] + bias;
    hid[1][et] = acc[1] + bias;
  }

  // ====== Phase B2: W1 = |H1 @ w1b + b1b|; hidden += q[:,a] * W1[:,a,:] ======
#pragma unroll 1
  for (int a = 0; a < 8; ++a) {
#pragma unroll
    for (int et = 0; et < 4; ++et) {
      int ct = a * 4 + et;
      floatx4 acc[2];
      gemm16(W + OFF_T1B, hA, ct, acc);
      float bias = b1b[ct * 16 + l15];
#pragma unroll
      for (int rt = 0; rt < 2; ++rt)
#pragma unroll
        for (int i = 0; i < 4; ++i) {
          float w1v = fabsf(acc[rt][i] + bias);
          float qv  = q_s[wid][(rt * 16 + quad * 4 + i) * 8 + a];
          hid[rt][et][i] += qv * w1v;
        }
    }
  }
  // relu
#pragma unroll
  for (int rt = 0; rt < 2; ++rt)
#pragma unroll
    for (int et = 0; et < 4; ++et)
#pragma unroll
      for (int i = 0; i < 4; ++i) hid[rt][et][i] = fmaxf(hid[rt][et][i], 0.f);

  // ================= Phase C: H2 = elu(st @ w2a + b2a) -> LDS ================
#pragma unroll 2
  for (int ct = 0; ct < 16; ++ct) {
    floatx4 acc[2];
    gemm16(W + OFF_T2A, sA, ct, acc);
    float bias = b2a[ct * 16 + l15];
#pragma unroll
    for (int rt = 0; rt < 2; ++rt)
#pragma unroll
      for (int i = 0; i < 4; ++i) {
        float v = acc[rt][i] + bias;
        v = v > 0.f ? v : (__expf(v) - 1.f);
        h_s[wid * 32 + rt * 16 + quad * 4 + i][ct * 16 + l15] = (bf16_t)v;
      }
  }
#pragma unroll
  for (int rt = 0; rt < 2; ++rt)
#pragma unroll
    for (int ks = 0; ks < 8; ++ks)
      hA[rt][ks] = *(const bf16x8*)&h_s[lrow + rt * 16][ks * 32 + quad * 8];

  // ====== Phase D: W2 = |H2 @ w2b + b2b|; pj = sum_e hidden*W2 (partial) =====
  float pj[2][4] = {{0.f, 0.f, 0.f, 0.f}, {0.f, 0.f, 0.f, 0.f}};
#pragma unroll
  for (int et = 0; et < 4; ++et) {
    floatx4 acc[2];
    gemm16(W + OFF_T2B, hA, et, acc);
    float bias = b2b[et * 16 + l15];
#pragma unroll
    for (int rt = 0; rt < 2; ++rt)
#pragma unroll
      for (int i = 0; i < 4; ++i) {
        float w2v = fabsf(acc[rt][i] + bias);
        pj[rt][i] += hid[rt][et][i] * w2v;
      }
  }

  // == Phase E: HB = elu(st @ wb2a + bb2a); pb = HB @ wb2b (fused in epilogue) =
  float pb[2][4] = {{0.f, 0.f, 0.f, 0.f}, {0.f, 0.f, 0.f, 0.f}};
#pragma unroll 2
  for (int ct = 0; ct < 16; ++ct) {
    floatx4 acc[2];
    gemm16(W + OFF_TB2A, sA, ct, acc);
    float bias = bb2a[ct * 16 + l15];
    float wv   = wb2b[ct * 16 + l15];
#pragma unroll
    for (int rt = 0; rt < 2; ++rt)
#pragma unroll
      for (int i = 0; i < 4; ++i) {
        float v = acc[rt][i] + bias;
        v = v > 0.f ? v : (__expf(v) - 1.f);
        pb[rt][i] += v * wv;
      }
  }

  // ======= Reduce over 16 column lanes (same row), store joint output ========
  float bb2 = bb2b[0];
#pragma unroll
  for (int rt = 0; rt < 2; ++rt)
#pragma unroll
    for (int i = 0; i < 4; ++i) {
      float v = pj[rt][i] + pb[rt][i];
      v += __shfl_xor(v, 1);
      v += __shfl_xor(v, 2);
      v += __shfl_xor(v, 4);
      v += __shfl_xor(v, 8);
      if (l15 == 0) out[m0 + rt * 16 + quad * 4 + i] = v + bb2;
    }
}

// ---------------------------------------------------------------------------
extern "C" void kernel_launch(void* const* d_in, const int* in_sizes, int n_in,
                              void* d_out, int out_size, void* d_ws, size_t ws_size,
                              hipStream_t stream) {
  const float* q    = (const float*)d_in[0];
  const float* st   = (const float*)d_in[1];
  const float* w1a  = (const float*)d_in[2];
  const float* b1a  = (const float*)d_in[3];
  const float* w1b  = (const float*)d_in[4];
  const float* b1b  = (const float*)d_in[5];
  const float* w2a  = (const float*)d_in[6];
  const float* b2a  = (const float*)d_in[7];
  const float* w2b  = (const float*)d_in[8];
  const float* b2b  = (const float*)d_in[9];
  const float* wb1  = (const float*)d_in[10];
  const float* bb1  = (const float*)d_in[11];
  const float* wb2a = (const float*)d_in[12];
  const float* bb2a = (const float*)d_in[13];
  const float* wb2b = (const float*)d_in[14];
  const float* bb2b = (const float*)d_in[15];
  bf16_t* W = (bf16_t*)d_ws;

  hipLaunchKernelGGL(prep_weights, dim3((WS_ELEMS + 255) / 256), dim3(256), 0, stream,
                     w1a, w1b, w2a, w2b, wb1, wb2a, W);
  hipLaunchKernelGGL(mixing_fused, dim3(NTOT / 128), dim3(256), 0, stream,
                     q, st, W, b1a, b1b, b2a, b2b, bb1, bb2a, wb2b, bb2b, (float*)d_out);
}